// Round 10
// baseline (128.382 us; speedup 1.0000x reference)
//
#include <hip/hip_runtime.h>
#include <stdint.h>

#define NSTEP 365
#define NGRID 4000
#define CAPMIN 0.00125f
#define SMINV 0.0001f
#define PSTR_DW (NGRID * 88)
#define XSTR_DW (NGRID * 3)

// LDS layout (dwords), total 15872 dw = 63488 B:
//   raw ring:     4 regions x 1728 (5 slots x 320 params + 128 x)  [0, 6912)
//   derived ring: 2 regions x 5 slots x 768                        [6912, 14592)
//   staging ring: 2 regions x 640 (smq 320 | sme 320)              [14592, 15872)
#define RAW_REG  1728
#define X_OFF    1600
#define DER_BASE 6912
#define DER_SLOT 768            // dwords; 384 in float2 units
#define DER_REG  3840
#define STG_BASE 14592
#define STG_REG  640

typedef __attribute__((address_space(3))) uint32_t lds_u32_t;
typedef __attribute__((address_space(1))) uint32_t glb_u32_t;

__device__ __forceinline__ void dma4(const float* g, float* l) {
    __builtin_amdgcn_global_load_lds((const glb_u32_t*)(const void*)g,
                                     (lds_u32_t*)(void*)l, 4, 0, 0);
}

__device__ __forceinline__ float frcp(float x) { return __builtin_amdgcn_rcpf(x); }
__device__ __forceinline__ float fexp2(float x) { return __builtin_amdgcn_exp2f(x); }
__device__ __forceinline__ float flog2(float x) { return __builtin_amdgcn_logf(x); }

// ---- state wave: hoisted reads (named registers, static addresses) ----
#define RDS(j)                                                               \
    const float  c0_##j = rreg[(j) * 320 + lane];                            \
    const float  kz_##j = rreg[(j) * 320 + 256 + lane];                      \
    const float  Pp_##j = xreg[(j) * 24 + gl3];                              \
    const float  Ee_##j = xreg[(j) * 24 + gl3 + 2];                          \
    const float2 dA_##j = dreg[(j) * 384 + lane];                            \
    const float2 dB_##j = dreg[(j) * 384 + 64 + lane];                       \
    const float2 dC_##j = dreg[(j) * 384 + 128 + lane];                      \
    const float2 dD_##j = dreg[(j) * 384 + 192 + lane];                      \
    const float2 dE_##j = dreg[(j) * 384 + 256 + lane];                      \
    const float2 dF_##j = dreg[(j) * 384 + 320 + lane];

#define STEP(j) do {                                                         \
    const float uztwm = dA_##j.x, uzfwm = dA_##j.y;                          \
    const float inv_uztwm = dB_##j.x, inv_uzfwm = dB_##j.y;                  \
    const float inv_uzsum = dC_##j.x, lztwm = dC_##j.y;                      \
    const float inv_lztwm = dD_##j.x, pbase = dD_##j.y;                      \
    const float lzfwpm = dE_##j.x, lzfwsm = dE_##j.y;                        \
    const float pz = dF_##j.x, inv_defmax = dF_##j.y;                        \
    const float Ep = Ee_##j, kuz = kz_##j;                                   \
    const float qdir = c0_##j * Pp_##j;                                      \
    const float peff = Pp_##j - qdir;                                        \
    const float rud  = S2 * uztwm - S1 * uzfwm;                              \
    const float ru   = (rud > 0.0f) ? rud * inv_uzsum : 0.0f;                \
    const float euztw = fminf(S1 * inv_uztwm * Ep, S1);                      \
    const float twexu = (S1 >= uztwm) ? peff : 0.0f;                         \
    const float qsur  = (S2 >= uzfwm) ? twexu : 0.0f;                        \
    const float qint  = kuz * S2;                                            \
    const float euzfw = fminf(fmaxf(0.0f, Ep - euztw), S2);                  \
    const float deficit = fmaxf(1e-8f, lztwm - S3)                           \
                        + fmaxf(1e-8f, lzfwpm - S4)                          \
                        + fmaxf(1e-8f, lzfwsm - S5);                         \
    const float powterm = fexp2(e1 * flog2(deficit * inv_defmax));           \
    const float pc = fminf((pbase + pz * powterm) * (S2 * inv_uzfwm), S2);   \
    const float pctw  = (1.0f - pfree) * pc;                                 \
    const float elztw = fminf(S3 * inv_lztwm                                 \
                              * fmaxf(0.0f, Ep - euztw - euzfw), S3);        \
    const float twexl = (S3 >= lztwm) ? pctw : 0.0f;                         \
    const float aa  = fmaxf(0.0f, lzfwpm - S4) * lzfwsm;                     \
    const float bb  = fmaxf(0.0f, lzfwsm - S5) * lzfwpm;                     \
    const float den = aa + bb;                                               \
    const float pm  = lzfwpm + lzfwsm;                                       \
    const float fp  = ((den > 0.0f) ? aa : lzfwpm)                           \
                    * frcp((den > 0.0f) ? den : pm);                         \
    const float fs  = 1.0f - fp;                                             \
    const float twexlp = fp * twexl;                                         \
    const float twexls = fs * twexl;                                         \
    const float pcfwp  = pfree * fp * pc;                                    \
    const float pcfws  = pfree * fs * pc;                                    \
    const bool rlm = S3 * pm < (S4 + S5) * lztwm;                            \
    const float rlp = rlm ? (S4 * lztwm - S3 * lzfwpm) * inv_defmax : 0.0f;  \
    const float rls = rlm ? (S5 * lztwm - S3 * lzfwsm) * inv_defmax : 0.0f;  \
    const float qbfp = klzp * S4;                                            \
    const float qbfs = klzs * S5;                                            \
    S1 = fmaxf(S1 + peff + ru - euztw - twexu, SMINV);                       \
    S2 = fmaxf(S2 + twexu - euzfw - qsur - qint - ru - pc, SMINV);           \
    S3 = fmaxf(S3 + pctw + rlp + rls - elztw - twexl, SMINV);                \
    S4 = fmaxf(S4 + twexlp + pcfwp - rlp - qbfp, SMINV);                     \
    S5 = fmaxf(S5 + twexls + pcfws - rls - qbfs, SMINV);                     \
    stq[(j) * 64 + lane] = qdir + qsur + qint + qbfp + qbfs;                 \
    stq[320 + (j) * 64 + lane] = euztw + euzfw + elztw;                      \
} while (0)

__global__ __launch_bounds__(192, 1) void sacsma_kernel(
    const float* __restrict__ x,     // [NSTEP][NGRID][3]
    const float* __restrict__ par,   // [NSTEP][NGRID][11][8]
    float* __restrict__ out)         // [NSTEP][NGRID][2]
{
    __shared__ __align__(16) float lds[15872];   // 63488 B

    const int wave = threadIdx.x >> 6;
    const int lane = threadIdx.x & 63;
    const int g0   = blockIdx.x * 8;
    const int gl   = lane >> 3;
    const int mu   = lane & 7;
    const int g    = g0 + gl;

    if (wave == 0) {
        // ===== DMA producer + output reducer (was idle ~70%) =====
        __builtin_amdgcn_s_setprio(0);
        const float* pp = par + (size_t)g * 88 + mu;
        // x gather: two per-lane-source DMAs cover 5 slots x 24 dw per batch
        const int tA = lane / 24;                      // 0..2
        const int rA = lane - 24 * tA;
        int idxB = lane + 64;
        int tB = idxB / 24;                            // 2..5
        int rB = idxB - 24 * tB;
        if (tB > 4) { tB = 4; rB = idxB - 120; }       // dup lanes, LDS dw unused
        const float* pxA = x + (size_t)tA * XSTR_DW + g0 * 3 + rA;
        const float* pxB = x + (size_t)tB * XSTR_DW + g0 * 3 + rB;

        #define ISSUE_BATCH(b) do {                                          \
            float* reg_ = lds + ((b) & 3) * RAW_REG;                         \
            const int tb_ = 5 * (b);                                         \
            _Pragma("unroll")                                                \
            for (int j = 0; j < 5; ++j) {                                    \
                const float* pj_ = pp + (size_t)(tb_ + j) * PSTR_DW;         \
                float* dst_ = reg_ + j * 320;                                \
                dma4(pj_,      dst_);                                        \
                dma4(pj_ + 8,  dst_ + 64);                                   \
                dma4(pj_ + 16, dst_ + 128);                                  \
                dma4(pj_ + 24, dst_ + 192);                                  \
                dma4(pj_ + 32, dst_ + 256);                                  \
            }                                                                \
            dma4(pxA + (size_t)tb_ * XSTR_DW, reg_ + X_OFF);                 \
            dma4(pxB + (size_t)tb_ * XSTR_DW, reg_ + X_OFF + 64);            \
        } while (0)

        #define REDUCE_STORE(b) do {                                         \
            if (lane < 40) {                                                 \
                const float* stg_ = lds + STG_BASE + ((b) & 1) * STG_REG;    \
                const int s_  = lane >> 3;                                   \
                const int gg_ = lane & 7;                                    \
                const float4 qa = *(const float4*)&stg_[s_ * 64 + gg_ * 8];  \
                const float4 qb = *(const float4*)&stg_[s_ * 64 + gg_ * 8 + 4];\
                const float4 ea = *(const float4*)&stg_[320 + s_ * 64 + gg_ * 8];\
                const float4 eb = *(const float4*)&stg_[320 + s_ * 64 + gg_ * 8 + 4];\
                const float qsum = ((qa.x + qa.y) + (qa.z + qa.w))           \
                                 + ((qb.x + qb.y) + (qb.z + qb.w));          \
                const float esum = ((ea.x + ea.y) + (ea.z + ea.w))           \
                                 + ((eb.x + eb.y) + (eb.z + eb.w));          \
                float2 o = make_float2(qsum * 0.125f, esum * 0.125f);        \
                *reinterpret_cast<float2*>(                                   \
                    out + ((size_t)(5 * (b) + s_) * NGRID + g0 + gg_) * 2) = o;\
            }                                                                \
        } while (0)

        ISSUE_BATCH(0);   // prologue

        for (int ip = 0; ip < 75; ++ip) {
            if (ip >= 3)
                REDUCE_STORE(ip - 3);                  // batches 0..71
            if (ip <= 71) {
                ISSUE_BATCH(ip + 1);                   // batches 1..72
                // batch ip (issued one full iteration ago) must be retired;
                // the 27 newest outstanding are batch ip+1's (FIFO, m135).
                asm volatile("s_waitcnt vmcnt(27)" ::: "memory");
            } else {
                asm volatile("s_waitcnt vmcnt(0)" ::: "memory");
            }
            asm volatile("s_barrier" ::: "memory");
        }
        REDUCE_STORE(72);                              // tail: after last barrier
    } else if (wave == 1) {
        // ===== transform wave: raw -> derived (param-only math, off the S-chain) =====
        __builtin_amdgcn_s_setprio(1);
        const float* ps = par + ((size_t)(NSTEP - 1) * NGRID + g) * 88 + mu;
        const float f3   = 0.005f + ps[6 * 8] * 0.99f;
        const float f4   = 0.005f + ps[7 * 8] * 0.99f;
        const float klzp = ps[9 * 8];
        const float klzs = ps[10 * 8];

        for (int i = 0; i < 75; ++i) {
            if (i >= 1 && i <= 73) {
                const int b = i - 1;                   // batches 0..72
                const float* rreg = lds + (b & 3) * RAW_REG;
                float* dregf = lds + DER_BASE + (b & 1) * DER_REG;
                #pragma unroll
                for (int j = 0; j < 5; ++j) {
                    const float* rb = rreg + j * 320;
                    float2* db = reinterpret_cast<float2*>(dregf + j * DER_SLOT);

                    const float c1 = rb[64 + lane];
                    const float c2 = rb[128 + lane];
                    const float c3 = rb[192 + lane];

                    const float smaxv = 1.0f + c1 * 1999.0f;
                    const float f1 = 0.005f + c2 * 0.99f;
                    const float f2 = 0.005f + c3 * 0.99f;
                    const float uztwm = f1 * smaxv;
                    float rem = smaxv - uztwm;
                    const float uzfwm = fmaxf(CAPMIN, f2 * rem);
                    rem -= uzfwm;
                    const float lztwm = fmaxf(CAPMIN, f3 * rem);
                    rem -= lztwm;
                    const float lzfwpm = fmaxf(CAPMIN, f4 * rem);
                    const float lzfwsm = fmaxf(CAPMIN, (1.0f - f4) * rem);
                    const float pbase = lzfwpm * klzp + lzfwsm * klzs;
                    const float pz = fminf(lztwm + lzfwsm * (1.0f - klzs)
                                           + lzfwpm * (1.0f - klzp),
                                           100000.0f * pbase);
                    const float inv_uztwm = frcp(uztwm);
                    const float inv_uzfwm = frcp(uzfwm);
                    const float inv_lztwm = frcp(lztwm);
                    const float inv_uzsum = frcp(uztwm + uzfwm);
                    const float inv_defmax = frcp(lztwm + lzfwpm + lzfwsm);

                    db[0 * 64 + lane] = make_float2(uztwm, uzfwm);
                    db[1 * 64 + lane] = make_float2(inv_uztwm, inv_uzfwm);
                    db[2 * 64 + lane] = make_float2(inv_uzsum, lztwm);
                    db[3 * 64 + lane] = make_float2(inv_lztwm, pbase);
                    db[4 * 64 + lane] = make_float2(lzfwpm, lzfwsm);
                    db[5 * 64 + lane] = make_float2(pz, inv_defmax);
                }
                asm volatile("s_waitcnt lgkmcnt(0)" ::: "memory");
            }
            asm volatile("s_barrier" ::: "memory");
        }
    } else {
        // ===== state wave: pure recurrence; highest priority (chain owner) =====
        __builtin_amdgcn_s_setprio(2);
        const float* ps = par + ((size_t)(NSTEP - 1) * NGRID + g) * 88 + mu;
        const float e1    = 1.0f + ps[5 * 8] * 7.0f;
        const float pfree = ps[8 * 8];
        const float klzp  = ps[9 * 8];
        const float klzs  = ps[10 * 8];

        float S1 = 0.001f, S2 = 0.001f, S3 = 0.001f, S4 = 0.001f, S5 = 0.001f;
        const int gl3 = gl * 3;

        for (int i = 0; i < 75; ++i) {
            if (i >= 2) {
                const int b = i - 2;                   // batches 0..72
                const float* rreg = lds + (b & 3) * RAW_REG;
                const float* xreg = rreg + X_OFF;
                const float2* dreg = reinterpret_cast<const float2*>(
                    lds + DER_BASE + (b & 1) * DER_REG);
                float* stq = lds + STG_BASE + (b & 1) * STG_REG;

                RDS(0) RDS(1) RDS(2) RDS(3) RDS(4)
                STEP(0); STEP(1); STEP(2); STEP(3); STEP(4);

                // staging writes must be LDS-complete before the barrier
                asm volatile("s_waitcnt lgkmcnt(0)" ::: "memory");
            }
            asm volatile("s_barrier" ::: "memory");
        }
    }
}

extern "C" void kernel_launch(void* const* d_in, const int* in_sizes, int n_in,
                              void* d_out, int out_size, void* d_ws, size_t ws_size,
                              hipStream_t stream) {
    const float* x   = (const float*)d_in[0];   // (365, 4000, 3)
    const float* par = (const float*)d_in[1];   // (365, 4000, 11, 8)
    float* out = (float*)d_out;                 // (365, 4000, 2)

    sacsma_kernel<<<NGRID / 8, 192, 0, stream>>>(x, par, out);  // 500 WGs x 3 waves
}

// Round 11
// 128.092 us; speedup vs baseline: 1.0023x; 1.0023x over previous
//
#include <hip/hip_runtime.h>
#include <stdint.h>

#define NSTEP 365
#define NGRID 4000
#define CAPMIN 0.00125f
#define SMINV 0.0001f
#define PSTR_DW (NGRID * 88)
#define XSTR_DW (NGRID * 3)

// LDS layout (dwords), total 15872 dw = 63488 B:
//   raw ring:     4 regions x 1728 (5 slots x 320 params + 128 x)  [0, 6912)
//   derived ring: 2 regions x 5 slots x 768                        [6912, 14592)
//   staging ring: 2 regions x 640 (smq 320 | sme 320)              [14592, 15872)
#define RAW_REG  1728
#define X_OFF    1600
#define DER_BASE 6912
#define DER_SLOT 768            // dwords; 384 in float2 units
#define DER_REG  3840
#define STG_BASE 14592
#define STG_REG  640

typedef __attribute__((address_space(3))) uint32_t lds_u32_t;
typedef __attribute__((address_space(1))) uint32_t glb_u32_t;

__device__ __forceinline__ void dma4(const float* g, float* l) {
    __builtin_amdgcn_global_load_lds((const glb_u32_t*)(const void*)g,
                                     (lds_u32_t*)(void*)l, 4, 0, 0);
}

__device__ __forceinline__ float frcp(float x) { return __builtin_amdgcn_rcpf(x); }
__device__ __forceinline__ float fexp2(float x) { return __builtin_amdgcn_exp2f(x); }
__device__ __forceinline__ float flog2(float x) { return __builtin_amdgcn_logf(x); }

// ---- state wave: hoisted reads (named registers, static addresses) ----
#define RDS(j)                                                               \
    const float  c0_##j = rreg[(j) * 320 + lane];                            \
    const float  kz_##j = rreg[(j) * 320 + 256 + lane];                      \
    const float  Pp_##j = xreg[(j) * 24 + gl3];                              \
    const float  Ee_##j = xreg[(j) * 24 + gl3 + 2];                          \
    const float2 dA_##j = dreg[(j) * 384 + lane];                            \
    const float2 dB_##j = dreg[(j) * 384 + 64 + lane];                       \
    const float2 dC_##j = dreg[(j) * 384 + 128 + lane];                      \
    const float2 dD_##j = dreg[(j) * 384 + 192 + lane];                      \
    const float2 dE_##j = dreg[(j) * 384 + 256 + lane];                      \
    const float2 dF_##j = dreg[(j) * 384 + 320 + lane];

#define STEP(j) do {                                                         \
    const float uztwm = dA_##j.x, uzfwm = dA_##j.y;                          \
    const float inv_uztwm = dB_##j.x, inv_uzfwm = dB_##j.y;                  \
    const float inv_uzsum = dC_##j.x, lztwm = dC_##j.y;                      \
    const float inv_lztwm = dD_##j.x, pbase = dD_##j.y;                      \
    const float lzfwpm = dE_##j.x, lzfwsm = dE_##j.y;                        \
    const float pz = dF_##j.x, inv_defmax = dF_##j.y;                        \
    const float Ep = Ee_##j, kuz = kz_##j;                                   \
    const float qdir = c0_##j * Pp_##j;                                      \
    const float peff = Pp_##j - qdir;                                        \
    const float rud  = S2 * uztwm - S1 * uzfwm;                              \
    const float ru   = (rud > 0.0f) ? rud * inv_uzsum : 0.0f;                \
    const float euztw = fminf(S1 * inv_uztwm * Ep, S1);                      \
    const float twexu = (S1 >= uztwm) ? peff : 0.0f;                         \
    const float qsur  = (S2 >= uzfwm) ? twexu : 0.0f;                        \
    const float qint  = kuz * S2;                                            \
    const float euzfw = fminf(fmaxf(0.0f, Ep - euztw), S2);                  \
    const float deficit = fmaxf(1e-8f, lztwm - S3)                           \
                        + fmaxf(1e-8f, lzfwpm - S4)                          \
                        + fmaxf(1e-8f, lzfwsm - S5);                         \
    const float powterm = fexp2(e1 * flog2(deficit * inv_defmax));           \
    const float pc = fminf((pbase + pz * powterm) * (S2 * inv_uzfwm), S2);   \
    const float pctw  = (1.0f - pfree) * pc;                                 \
    const float elztw = fminf(S3 * inv_lztwm                                 \
                              * fmaxf(0.0f, Ep - euztw - euzfw), S3);        \
    const float twexl = (S3 >= lztwm) ? pctw : 0.0f;                         \
    const float aa  = fmaxf(0.0f, lzfwpm - S4) * lzfwsm;                     \
    const float bb  = fmaxf(0.0f, lzfwsm - S5) * lzfwpm;                     \
    const float den = aa + bb;                                               \
    const float pm  = lzfwpm + lzfwsm;                                       \
    const float fp  = ((den > 0.0f) ? aa : lzfwpm)                           \
                    * frcp((den > 0.0f) ? den : pm);                         \
    const float fs  = 1.0f - fp;                                             \
    const float twexlp = fp * twexl;                                         \
    const float twexls = fs * twexl;                                         \
    const float pcfwp  = pfree * fp * pc;                                    \
    const float pcfws  = pfree * fs * pc;                                    \
    const bool rlm = S3 * pm < (S4 + S5) * lztwm;                            \
    const float rlp = rlm ? (S4 * lztwm - S3 * lzfwpm) * inv_defmax : 0.0f;  \
    const float rls = rlm ? (S5 * lztwm - S3 * lzfwsm) * inv_defmax : 0.0f;  \
    const float qbfp = klzp * S4;                                            \
    const float qbfs = klzs * S5;                                            \
    S1 = fmaxf(S1 + peff + ru - euztw - twexu, SMINV);                       \
    S2 = fmaxf(S2 + twexu - euzfw - qsur - qint - ru - pc, SMINV);           \
    S3 = fmaxf(S3 + pctw + rlp + rls - elztw - twexl, SMINV);                \
    S4 = fmaxf(S4 + twexlp + pcfwp - rlp - qbfp, SMINV);                     \
    S5 = fmaxf(S5 + twexls + pcfws - rls - qbfs, SMINV);                     \
    stq[(j) * 64 + lane] = qdir + qsur + qint + qbfp + qbfs;                 \
    stq[320 + (j) * 64 + lane] = euztw + euzfw + elztw;                      \
} while (0)

__global__ __launch_bounds__(192, 1) void sacsma_kernel(
    const float* __restrict__ x,     // [NSTEP][NGRID][3]
    const float* __restrict__ par,   // [NSTEP][NGRID][11][8]
    float* __restrict__ out)         // [NSTEP][NGRID][2]
{
    __shared__ __align__(16) float lds[15872];   // 63488 B

    const int wave = threadIdx.x >> 6;
    const int lane = threadIdx.x & 63;
    const int g0   = blockIdx.x * 8;
    const int gl   = lane >> 3;
    const int mu   = lane & 7;
    const int g    = g0 + gl;

    if (wave == 0) {
        // ===== DMA producer + output reducer (was idle ~70%) =====
        __builtin_amdgcn_s_setprio(0);
        const float* pp = par + (size_t)g * 88 + mu;
        // x gather: two per-lane-source DMAs cover 5 slots x 24 dw per batch
        const int tA = lane / 24;                      // 0..2
        const int rA = lane - 24 * tA;
        int idxB = lane + 64;
        int tB = idxB / 24;                            // 2..5
        int rB = idxB - 24 * tB;
        if (tB > 4) { tB = 4; rB = idxB - 120; }       // dup lanes, LDS dw unused
        const float* pxA = x + (size_t)tA * XSTR_DW + g0 * 3 + rA;
        const float* pxB = x + (size_t)tB * XSTR_DW + g0 * 3 + rB;

        #define ISSUE_BATCH(b) do {                                          \
            float* reg_ = lds + ((b) & 3) * RAW_REG;                         \
            const int tb_ = 5 * (b);                                         \
            _Pragma("unroll")                                                \
            for (int j = 0; j < 5; ++j) {                                    \
                const float* pj_ = pp + (size_t)(tb_ + j) * PSTR_DW;         \
                float* dst_ = reg_ + j * 320;                                \
                dma4(pj_,      dst_);                                        \
                dma4(pj_ + 8,  dst_ + 64);                                   \
                dma4(pj_ + 16, dst_ + 128);                                  \
                dma4(pj_ + 24, dst_ + 192);                                  \
                dma4(pj_ + 32, dst_ + 256);                                  \
            }                                                                \
            dma4(pxA + (size_t)tb_ * XSTR_DW, reg_ + X_OFF);                 \
            dma4(pxB + (size_t)tb_ * XSTR_DW, reg_ + X_OFF + 64);            \
        } while (0)

        #define REDUCE_STORE(b) do {                                         \
            if (lane < 40) {                                                 \
                const float* stg_ = lds + STG_BASE + ((b) & 1) * STG_REG;    \
                const int s_  = lane >> 3;                                   \
                const int gg_ = lane & 7;                                    \
                const float4 qa = *(const float4*)&stg_[s_ * 64 + gg_ * 8];  \
                const float4 qb = *(const float4*)&stg_[s_ * 64 + gg_ * 8 + 4];\
                const float4 ea = *(const float4*)&stg_[320 + s_ * 64 + gg_ * 8];\
                const float4 eb = *(const float4*)&stg_[320 + s_ * 64 + gg_ * 8 + 4];\
                const float qsum = ((qa.x + qa.y) + (qa.z + qa.w))           \
                                 + ((qb.x + qb.y) + (qb.z + qb.w));          \
                const float esum = ((ea.x + ea.y) + (ea.z + ea.w))           \
                                 + ((eb.x + eb.y) + (eb.z + eb.w));          \
                float2 o = make_float2(qsum * 0.125f, esum * 0.125f);        \
                *reinterpret_cast<float2*>(                                   \
                    out + ((size_t)(5 * (b) + s_) * NGRID + g0 + gg_) * 2) = o;\
            }                                                                \
        } while (0)

        ISSUE_BATCH(0);   // prologue

        for (int ip = 0; ip < 75; ++ip) {
            if (ip >= 3)
                REDUCE_STORE(ip - 3);                  // batches 0..71
            if (ip <= 71) {
                ISSUE_BATCH(ip + 1);                   // batches 1..72
                // batch ip (issued one full iteration ago) must be retired;
                // the 27 newest outstanding are batch ip+1's (FIFO, m135).
                asm volatile("s_waitcnt vmcnt(27)" ::: "memory");
            } else {
                asm volatile("s_waitcnt vmcnt(0)" ::: "memory");
            }
            asm volatile("s_barrier" ::: "memory");
        }
        REDUCE_STORE(72);                              // tail: after last barrier
    } else if (wave == 1) {
        // ===== transform wave: raw -> derived (param-only math, off the S-chain) =====
        __builtin_amdgcn_s_setprio(1);
        const float* ps = par + ((size_t)(NSTEP - 1) * NGRID + g) * 88 + mu;
        const float f3   = 0.005f + ps[6 * 8] * 0.99f;
        const float f4   = 0.005f + ps[7 * 8] * 0.99f;
        const float klzp = ps[9 * 8];
        const float klzs = ps[10 * 8];

        for (int i = 0; i < 75; ++i) {
            if (i >= 1 && i <= 73) {
                const int b = i - 1;                   // batches 0..72
                const float* rreg = lds + (b & 3) * RAW_REG;
                float* dregf = lds + DER_BASE + (b & 1) * DER_REG;
                #pragma unroll
                for (int j = 0; j < 5; ++j) {
                    const float* rb = rreg + j * 320;
                    float2* db = reinterpret_cast<float2*>(dregf + j * DER_SLOT);

                    const float c1 = rb[64 + lane];
                    const float c2 = rb[128 + lane];
                    const float c3 = rb[192 + lane];

                    const float smaxv = 1.0f + c1 * 1999.0f;
                    const float f1 = 0.005f + c2 * 0.99f;
                    const float f2 = 0.005f + c3 * 0.99f;
                    const float uztwm = f1 * smaxv;
                    float rem = smaxv - uztwm;
                    const float uzfwm = fmaxf(CAPMIN, f2 * rem);
                    rem -= uzfwm;
                    const float lztwm = fmaxf(CAPMIN, f3 * rem);
                    rem -= lztwm;
                    const float lzfwpm = fmaxf(CAPMIN, f4 * rem);
                    const float lzfwsm = fmaxf(CAPMIN, (1.0f - f4) * rem);
                    const float pbase = lzfwpm * klzp + lzfwsm * klzs;
                    const float pz = fminf(lztwm + lzfwsm * (1.0f - klzs)
                                           + lzfwpm * (1.0f - klzp),
                                           100000.0f * pbase);
                    const float inv_uztwm = frcp(uztwm);
                    const float inv_uzfwm = frcp(uzfwm);
                    const float inv_lztwm = frcp(lztwm);
                    const float inv_uzsum = frcp(uztwm + uzfwm);
                    const float inv_defmax = frcp(lztwm + lzfwpm + lzfwsm);

                    db[0 * 64 + lane] = make_float2(uztwm, uzfwm);
                    db[1 * 64 + lane] = make_float2(inv_uztwm, inv_uzfwm);
                    db[2 * 64 + lane] = make_float2(inv_uzsum, lztwm);
                    db[3 * 64 + lane] = make_float2(inv_lztwm, pbase);
                    db[4 * 64 + lane] = make_float2(lzfwpm, lzfwsm);
                    db[5 * 64 + lane] = make_float2(pz, inv_defmax);
                }
                asm volatile("s_waitcnt lgkmcnt(0)" ::: "memory");
            }
            asm volatile("s_barrier" ::: "memory");
        }
    } else {
        // ===== state wave: pure recurrence; highest priority (chain owner) =====
        __builtin_amdgcn_s_setprio(2);
        const float* ps = par + ((size_t)(NSTEP - 1) * NGRID + g) * 88 + mu;
        const float e1    = 1.0f + ps[5 * 8] * 7.0f;
        const float pfree = ps[8 * 8];
        const float klzp  = ps[9 * 8];
        const float klzs  = ps[10 * 8];

        float S1 = 0.001f, S2 = 0.001f, S3 = 0.001f, S4 = 0.001f, S5 = 0.001f;
        const int gl3 = gl * 3;

        for (int i = 0; i < 75; ++i) {
            if (i >= 2) {
                const int b = i - 2;                   // batches 0..72
                const float* rreg = lds + (b & 3) * RAW_REG;
                const float* xreg = rreg + X_OFF;
                const float2* dreg = reinterpret_cast<const float2*>(
                    lds + DER_BASE + (b & 1) * DER_REG);
                float* stq = lds + STG_BASE + (b & 1) * STG_REG;

                RDS(0) RDS(1) RDS(2) RDS(3) RDS(4)
                STEP(0); STEP(1); STEP(2); STEP(3); STEP(4);

                // staging writes must be LDS-complete before the barrier
                asm volatile("s_waitcnt lgkmcnt(0)" ::: "memory");
            }
            asm volatile("s_barrier" ::: "memory");
        }
    }
}

extern "C" void kernel_launch(void* const* d_in, const int* in_sizes, int n_in,
                              void* d_out, int out_size, void* d_ws, size_t ws_size,
                              hipStream_t stream) {
    const float* x   = (const float*)d_in[0];   // (365, 4000, 3)
    const float* par = (const float*)d_in[1];   // (365, 4000, 11, 8)
    float* out = (float*)d_out;                 // (365, 4000, 2)

    sacsma_kernel<<<NGRID / 8, 192, 0, stream>>>(x, par, out);  // 500 WGs x 3 waves
}